// Round 10
// baseline (3689.801 us; speedup 1.0000x reference)
//
#include <hip/hip_runtime.h>
#include <hip/hip_bf16.h>

// PeepholeLSTM: SEQ=512, BATCH=64, IN=512, HS=1024, FORGET_BIAS=0
// out = [hidden_seq (512*64*1024) | c_T (64*1024) | h_T (64*1024)] f32
//
// Round-10: round-9 + per-XCD relay broadcast.
//   Round-9 showed the structure is LLC-BW-bound: 128 WGs x 256KB tagged-h = 32MB/step
//   at 6.3 TB/s = 5.1us/step, and the plain-load L2 path self-poisons (early fetch
//   installs stale-tag lines; bypass retries never refresh L2).
//   Fix: cluster = bid&7 (XCD round-robin lore), crank = bid>>3. Each WG relays its
//   16KB slice of hqt (tag-gated sc0sc1 read -> normal store) into a per-cluster
//   staging buffer that stays DIRTY in the local XCD L2. Consumers read staging:
//   plain first-try + sc0 retries (local-dirty lines are coherent within the XCD;
//   stores update L2 in place -> retries converge, no poisoning). LLC/step: 32MB->2MB.
//   Tags still gate everything; per-group fallback to sc0sc1-from-hqt (round-9 path,
//   always correct). Health counter disables relay permanently if mapping is wrong
//   (bounded downside = round-9 perf). No __syncthreads except one per step to make
//   own-relay stores WG-visible.

#define SEQN 512
#define BATCH 64
#define INDIM 512
#define HSZ 1024
#define NWG 128
#define DEPTH 64
#define SDEPTH 8

typedef __attribute__((ext_vector_type(8))) short s16x8;
typedef __attribute__((ext_vector_type(4))) float f32x4;
typedef __attribute__((ext_vector_type(2))) float f32x2;
typedef __attribute__((ext_vector_type(4))) int i32x4;
typedef unsigned long long u64;

__device__ __forceinline__ short f2bf(float f) {
  __hip_bfloat16 b = __float2bfloat16(f);
  short s;
  __builtin_memcpy(&s, &b, 2);
  return s;
}
__device__ __forceinline__ float sigf(float x) { return 1.f / (1.f + __expf(-x)); }
__device__ __forceinline__ float tanh_fast(float x) { return 2.f / (1.f + __expf(-2.f * x)) - 1.f; }

// ---------------------------------------------------------------------------
// prep_w: one thread per W element. col = gate*1024 + hidx; hidx = g*8+off; pc = off*4+gate.
__global__ __launch_bounds__(256) void prep_w(const float* __restrict__ W,
                                              short* __restrict__ WxP,
                                              short* __restrict__ WhP) {
  int idx = blockIdx.x * 256 + threadIdx.x;
  if (idx >= 1536 * 4096) return;
  int k = idx >> 12, col = idx & 4095;
  short b = f2bf(W[idx]);
  int gate = col >> 10, hidx = col & 1023;
  int g = hidx >> 3, off = hidx & 7;
  int pc = off * 4 + gate;
  if (k < 512) {
    WxP[(size_t)(((g * 64 + (k >> 3)) * 32 + pc) << 3) + (k & 7)] = b;
  } else {
    int kh = k - 512;
    WhP[(size_t)(((g * 128 + (kh >> 3)) * 32 + pc) << 3) + (kh & 7)] = b;
  }
}

// ---------------------------------------------------------------------------
// prep_x: x[t][m][k] f32 -> xbp[t][kb][m][8] bf16.
__global__ __launch_bounds__(256) void prep_x(const float* __restrict__ x,
                                              short* __restrict__ xbp) {
  int idx = blockIdx.x * 256 + threadIdx.x;
  if (idx >= SEQN * 64 * 64) return;
  int kb = idx & 63, m = (idx >> 6) & 63, t = idx >> 12;
  const float4* xp = reinterpret_cast<const float4*>(x + ((size_t)t * 64 + m) * 512 + kb * 8);
  float4 a = xp[0], c = xp[1];
  s16x8 v;
  v[0] = f2bf(a.x); v[1] = f2bf(a.y); v[2] = f2bf(a.z); v[3] = f2bf(a.w);
  v[4] = f2bf(c.x); v[5] = f2bf(c.y); v[6] = f2bf(c.z); v[7] = f2bf(c.w);
  reinterpret_cast<s16x8*>(xbp)[((size_t)t * 64 + kb) * 64 + m] = v;
}

// ---------------------------------------------------------------------------
// lstm_seq: 128 WGs x 256. Wave w: batch rows [16w,16w+16). Lane l: m = w*16+(l&15),
// q4 = l>>4, hidden cols c0 = 8g+q4, c1 = c0+4, all 4 gates.
// hqt[t&63][gsrc 128][m 64][j 4] u64 = tag(t)<<32 | h[8gsrc+j+4]<<16 | h[8gsrc+j].
// stg[cluster 8][t&7][same 32768-u64 layout]: relay copy, dirty in local XCD L2.
__global__ __launch_bounds__(256, 1) void lstm_seq(const short* __restrict__ xbp,
                                                   const short* __restrict__ WhP,
                                                   const short* __restrict__ WxP,
                                                   const float* __restrict__ bias,
                                                   const float* __restrict__ peep_i,
                                                   const float* __restrict__ peep_f,
                                                   const float* __restrict__ peep_o,
                                                   u64* hqt,
                                                   u64* stg,
                                                   float* __restrict__ out) {
  __shared__ short WhS[32768];   // 64KB [kb 128][pc 32][8]
  __shared__ short WxS[16384];   // 32KB [kb  64][pc 32][8]
  __shared__ float outS[512];    //  2KB
  __shared__ int fbS;            // health accumulator
  int g = blockIdx.x;
  int tid = threadIdx.x, w = tid >> 6, l = tid & 63;
  int cluster = g & 7, crank = g >> 3;
  u64* stgc = stg + (size_t)cluster * (SDEPTH * 32768);
  {
    const s16x8* src = reinterpret_cast<const s16x8*>(WhP + (size_t)g * 32768);
    s16x8* dst = reinterpret_cast<s16x8*>(WhS);
#pragma unroll
    for (int i = 0; i < 16; ++i) dst[i * 256 + tid] = src[i * 256 + tid];
    const s16x8* src2 = reinterpret_cast<const s16x8*>(WxP + (size_t)g * 16384);
    s16x8* dst2 = reinterpret_cast<s16x8*>(WxS);
#pragma unroll
    for (int i = 0; i < 8; ++i) dst2[i * 256 + tid] = src2[i * 256 + tid];
  }
  if (tid == 0) fbS = 0;
  int m = w * 16 + (l & 15), q4 = l >> 4, l15 = l & 15;
  int c0 = g * 8 + q4, c1 = c0 + 4;
  float bi0 = bias[c0], bj0 = bias[1024 + c0], bf0 = bias[2048 + c0], bo0 = bias[3072 + c0];
  float bi1 = bias[c1], bj1 = bias[1024 + c1], bf1 = bias[2048 + c1], bo1 = bias[3072 + c1];
  float pi0 = peep_i[c0], pf0 = peep_f[c0], po0 = peep_o[c0];
  float pi1 = peep_i[c1], pf1 = peep_f[c1], po1 = peep_o[c1];
  float cr0 = 0.f, cr1 = 0.f;
  int relayok = 1, fellback = 0;
  s16x8* WhS16 = reinterpret_cast<s16x8*>(WhS);
  s16x8* WxS16 = reinterpret_cast<s16x8*>(WxS);
  __syncthreads();

#define TAGTEST(BANK)                                                                    \
  {                                                                                      \
    okv = true;                                                                          \
    _Pragma("unroll") for (int i2 = 0; i2 < 16; ++i2) okv &=                             \
        ((unsigned)BANK[i2][1] == (unsigned)t) & ((unsigned)BANK[i2][3] == (unsigned)t); \
  }
// first try: compiler-tracked plain loads (pipelined); from staging when relay healthy
#define LOADG(BANK, G)                                                                   \
  {                                                                                      \
    const u64* fdq_ = relayok ? sdq : rdq;                                               \
    _Pragma("unroll") for (int i = 0; i < 16; ++i) {                                     \
      int kb_ = ((G) * 8 + (i >> 1)) * 4 + q4;                                           \
      BANK[i] = *reinterpret_cast<const i32x4*>(fdq_ + kb_ * 256 + m * 4 + (i & 1) * 2); \
    }                                                                                    \
  }
// staging retry: sc0 (bypass L1, served by local L2 which holds relay's dirty lines)
#define SLOADG(BANK, G)                                                                  \
  {                                                                                      \
    _Pragma("unroll") for (int i = 0; i < 16; ++i) {                                     \
      int kb_ = ((G) * 8 + (i >> 1)) * 4 + q4;                                           \
      const u64* p_ = sdq + kb_ * 256 + m * 4 + (i & 1) * 2;                             \
      asm volatile("global_load_dwordx4 %0, %1, off sc0" : "=v"(BANK[i]) : "v"(p_));     \
    }                                                                                    \
    asm volatile("s_waitcnt vmcnt(0)" ::: "memory");                                     \
    __builtin_amdgcn_sched_barrier(0);                                                   \
  }
// truth fallback: sc0 sc1 from hqt (round-9 path, always correct)
#define RELOADG(BANK, G)                                                                 \
  {                                                                                      \
    _Pragma("unroll") for (int i = 0; i < 16; ++i) {                                     \
      int kb_ = ((G) * 8 + (i >> 1)) * 4 + q4;                                           \
      const u64* p_ = rdq + kb_ * 256 + m * 4 + (i & 1) * 2;                             \
      asm volatile("global_load_dwordx4 %0, %1, off sc0 sc1" : "=v"(BANK[i]) : "v"(p_)); \
    }                                                                                    \
    asm volatile("s_waitcnt vmcnt(0)" ::: "memory");                                     \
    __builtin_amdgcn_sched_barrier(0);                                                   \
  }
#define CHECKG(BANK, G)                                                                  \
  {                                                                                      \
    bool okv;                                                                            \
    TAGTEST(BANK);                                                                       \
    int rr = 0;                                                                          \
    while (relayok && !__all((int)okv) && rr < 4) {                                      \
      SLOADG(BANK, G);                                                                   \
      TAGTEST(BANK);                                                                     \
      ++rr;                                                                              \
    }                                                                                    \
    if (!__all((int)okv)) {                                                              \
      if (t >= 4) ++fellback;                                                            \
      int guard = 0;                                                                     \
      while (!__all((int)okv)) {                                                         \
        RELOADG(BANK, G);                                                                \
        TAGTEST(BANK);                                                                   \
        if (++guard > (1 << 13)) break; /* fail loud, never hang */                      \
      }                                                                                  \
    }                                                                                    \
  }
#define MFMAG(BANK, G)                                                                   \
  {                                                                                      \
    _Pragma("unroll") for (int kk2 = 0; kk2 < 8; ++kk2) {                                \
      int kb_ = ((G) * 8 + kk2) * 4 + q4;                                                \
      unsigned d0 = (unsigned)BANK[kk2 * 2][0], d1 = (unsigned)BANK[kk2 * 2][2];         \
      unsigned d2 = (unsigned)BANK[kk2 * 2 + 1][0], d3 = (unsigned)BANK[kk2 * 2 + 1][2]; \
      union { unsigned u[4]; s16x8 v; } bu;                                              \
      bu.u[0] = (d0 & 0xFFFFu) | (d1 << 16);                                             \
      bu.u[1] = (d2 & 0xFFFFu) | (d3 << 16);                                             \
      bu.u[2] = (d0 >> 16) | (d1 & 0xFFFF0000u);                                         \
      bu.u[3] = (d2 >> 16) | (d3 & 0xFFFF0000u);                                        \
      s16x8 a0 = WhS16[kb_ * 32 + l15];                                                  \
      s16x8 a1 = WhS16[kb_ * 32 + 16 + l15];                                             \
      acc0 = __builtin_amdgcn_mfma_f32_16x16x32_bf16(a0, bu.v, acc0, 0, 0, 0);           \
      acc1 = __builtin_amdgcn_mfma_f32_16x16x32_bf16(a1, bu.v, acc1, 0, 0, 0);           \
    }                                                                                    \
  }

  for (int t = 0; t < SEQN; ++t) {
    f32x4 acc0 = {0.f, 0.f, 0.f, 0.f}, acc1 = {0.f, 0.f, 0.f, 0.f};
    // ---- x-projection (h-independent; fills publish-visibility window) ----
    {
      const s16x8* xt = reinterpret_cast<const s16x8*>(xbp) + (size_t)t * 4096;
#pragma unroll 4
      for (int kk = 0; kk < 16; ++kk) {
        int kb = kk * 4 + q4;
        s16x8 bx = xt[kb * 64 + m];
        s16x8 a0 = WxS16[kb * 32 + l15];
        s16x8 a1 = WxS16[kb * 32 + 16 + l15];
        acc0 = __builtin_amdgcn_mfma_f32_16x16x32_bf16(a0, bx, acc0, 0, 0, 0);
        acc1 = __builtin_amdgcn_mfma_f32_16x16x32_bf16(a1, bx, acc1, 0, 0, 0);
      }
    }
    if (t > 0) {
      const u64* rdq = hqt + (size_t)(t & (DEPTH - 1)) * 32768;
      const u64* sdq = stgc + (size_t)(t & (SDEPTH - 1)) * 32768;
      // ---- relay: copy my 16KB slice (gsrc 8*crank..+8) from hqt -> local staging ----
      if (relayok) {
        const u64* rsrc = rdq + crank * 2048 + tid * 8;
        u64* rdst = const_cast<u64*>(sdq) + crank * 2048 + tid * 8;
        i32x4 rv[4];
        int guard = 0;
        while (true) {
#pragma unroll
          for (int i = 0; i < 4; ++i) {
            const u64* p_ = rsrc + i * 2;
            asm volatile("global_load_dwordx4 %0, %1, off sc0 sc1" : "=v"(rv[i]) : "v"(p_));
          }
          asm volatile("s_waitcnt vmcnt(0)" ::: "memory");
          __builtin_amdgcn_sched_barrier(0);
          bool ok = true;
#pragma unroll
          for (int i = 0; i < 4; ++i)
            ok &= ((unsigned)rv[i][1] == (unsigned)t) & ((unsigned)rv[i][3] == (unsigned)t);
          if (__all((int)ok)) break;
          if (++guard > (1 << 13)) break;  // fail loud; consumers fall back anyway
        }
#pragma unroll
        for (int i = 0; i < 4; ++i) *reinterpret_cast<i32x4*>(rdst + i * 2) = rv[i];
        __syncthreads();  // own-part stores drained to L2 & visible to whole WG
      }
      // ---- consume: 4 pipelined groups, 2 reg banks ----
      i32x4 hA[16], hB[16];
      LOADG(hA, 0);
      LOADG(hB, 1);
      CHECKG(hA, 0);
      MFMAG(hA, 0);
      LOADG(hA, 2);
      CHECKG(hB, 1);
      MFMAG(hB, 1);
      LOADG(hB, 3);
      CHECKG(hA, 2);
      MFMAG(hA, 2);
      CHECKG(hB, 3);
      MFMAG(hB, 3);
    }
    // ---- elementwise (lane-local: all 4 gates of c0 and c1) ----
    float i0 = sigf(acc0[0] + bi0 + cr0 * pi0);
    float f0 = sigf(acc0[2] + bf0 + cr0 * pf0);
    float cn0 = f0 * cr0 + i0 * tanh_fast(acc0[1] + bj0);
    float o0 = sigf(acc0[3] + bo0 + cn0 * po0);
    float h0 = o0 * tanh_fast(cn0);
    cr0 = cn0;
    float i1 = sigf(acc1[0] + bi1 + cr1 * pi1);
    float f1 = sigf(acc1[2] + bf1 + cr1 * pf1);
    float cn1 = f1 * cr1 + i1 * tanh_fast(acc1[1] + bj1);
    float o1 = sigf(acc1[3] + bo1 + cn1 * po1);
    float h1 = o1 * tanh_fast(cn1);
    cr1 = cn1;
    // ---- publish tagged h_t (tag t+1) into hqt slot (t+1)&63: ONE exchange/lane ----
    {
      u64 q = ((u64)(unsigned)(t + 1) << 32) |
              ((u64)(unsigned short)f2bf(h1) << 16) | (u64)(unsigned short)f2bf(h0);
      (void)__hip_atomic_exchange(
          hqt + (size_t)((t + 1) & (DEPTH - 1)) * 32768 + g * 256 + m * 4 + q4, q,
          __ATOMIC_RELAXED, __HIP_MEMORY_SCOPE_AGENT);
    }
    // ---- coalesced hidden_seq store via wave-local LDS stage ----
    outS[w * 128 + l15 * 8 + q4] = h0;
    outS[w * 128 + l15 * 8 + q4 + 4] = h1;
    {
      f32x2 v = *reinterpret_cast<f32x2*>(&outS[w * 128 + (l >> 2) * 8 + (l & 3) * 2]);
      int row = w * 16 + (l >> 2), col = g * 8 + (l & 3) * 2;
      __builtin_nontemporal_store(
          v, reinterpret_cast<f32x2*>(out + (size_t)t * 65536 + (size_t)row * 1024 + col));
    }
    if (t == SEQN - 1) {
      out[33554432ull + (size_t)m * 1024 + c0] = cn0;  // c_T
      out[33554432ull + (size_t)m * 1024 + c1] = cn1;
      out[33619968ull + (size_t)m * 1024 + c0] = h0;   // h_T
      out[33619968ull + (size_t)m * 1024 + c1] = h1;
    }
    // ---- one-time health decision: wrong cluster mapping -> permanent round-9 mode ----
    if (t == 8) {
      if (l == 0) atomicAdd(&fbS, fellback);
      __syncthreads();
      if (fbS > 16) relayok = 0;
    }
  }
#undef TAGTEST
#undef LOADG
#undef SLOADG
#undef RELOADG
#undef CHECKG
#undef MFMAG
}

// ---------------------------------------------------------------------------
extern "C" void kernel_launch(void* const* d_in, const int* in_sizes, int n_in,
                              void* d_out, int out_size, void* d_ws, size_t ws_size,
                              hipStream_t stream) {
  const float* x      = (const float*)d_in[0];
  const float* W      = (const float*)d_in[1];
  const float* bias   = (const float*)d_in[2];
  const float* peep_i = (const float*)d_in[3];
  const float* peep_f = (const float*)d_in[4];
  const float* peep_o = (const float*)d_in[5];
  char* ws = (char*)d_ws;
  short* WxP = (short*)(ws);                   //  4194304 B
  short* WhP = (short*)(ws + 4194304ull);      //  8388608 B
  short* xbp = (short*)(ws + 12582912ull);     // 33554432 B
  u64* hqt   = (u64*)(ws + 46137344ull);       // 16777216 B (64 x 256KB tagged h slots)
  u64* stg   = (u64*)(ws + 62914560ull);       // 16777216 B (8 clusters x 8 x 256KB staging)
  // zero hqt tags every launch: stale tags from a prior replay must never alias this
  // run's expected tag sequence. Staging needs no memset: slot (t&7) is overwritten by
  // this run's relay before its tags can match (stale values are from steps != t).
  (void)hipMemsetAsync(hqt, 0, 16777216ull, stream);
  prep_w<<<24576, 256, 0, stream>>>(W, WxP, WhP);
  prep_x<<<8192, 256, 0, stream>>>(x, xbp);
  lstm_seq<<<NWG, 256, 0, stream>>>(xbp, WhP, WxP, bias, peep_i, peep_f, peep_o, hqt, stg,
                                    (float*)d_out);
}

// Round 11
// 3578.945 us; speedup vs baseline: 1.0310x; 1.0310x over previous
//
#include <hip/hip_runtime.h>
#include <hip/hip_bf16.h>

// PeepholeLSTM: SEQ=512, BATCH=64, IN=512, HS=1024, FORGET_BIAS=0
// out = [hidden_seq (512*64*1024) | c_T (64*1024) | h_T (64*1024)] f32
//
// Round-11: halve the LLC broadcast via pc=64 (16 hidden cols/WG), NWG=64.
//   Model (r9/r10): per-step LLC volume = NWG x slice = 1GB/pc -> pc is the only lever.
//   pc 32->64 => 32MB->16MB/step at ~6.3TB/s => ~2.6us/step floor.
//   Wh slice = 128KB LDS => Wx leaves LDS => x-projection precomputed by gemm_x into
//   XP[t][g][m][pc] bf16 (8KB/WG/step to read). Consumer protocol = round 9 verbatim
//   (tagged u64 [tag32|2bf16], plain first-try + sc0sc1 retry, 4 groups x 2 reg banks);
//   per chunk now 4 MFMAs (4 pc-blocks). Publish = 2 tagged exchanges/lane.
//   hqt (DEPTH=16, 4MB) OVERLAYS WxPT (dead after gemm_x; memset is stream-ordered).
//   Round-10 relay (L2 staging) refuted: stores flowed back to LLC (+1GB WRITE), revert.

#define SEQN 512
#define BATCH 64
#define INDIM 512
#define HSZ 1024
#define NWG 64
#define DEPTH 16

typedef __attribute__((ext_vector_type(8))) short s16x8;
typedef __attribute__((ext_vector_type(4))) short s16x4;
typedef __attribute__((ext_vector_type(4))) float f32x4;
typedef __attribute__((ext_vector_type(4))) int i32x4;
typedef unsigned long long u64;

__device__ __forceinline__ short f2bf(float f) {
  __hip_bfloat16 b = __float2bfloat16(f);
  short s;
  __builtin_memcpy(&s, &b, 2);
  return s;
}
__device__ __forceinline__ float bf2f(short s) {
  unsigned u = ((unsigned)(unsigned short)s) << 16;
  float f;
  __builtin_memcpy(&f, &u, 4);
  return f;
}
__device__ __forceinline__ float sigf(float x) { return 1.f / (1.f + __expf(-x)); }
__device__ __forceinline__ float tanh_fast(float x) { return 2.f / (1.f + __expf(-2.f * x)) - 1.f; }

// ---------------------------------------------------------------------------
// prep_w: col = gate*1024 + hidx; g = hidx>>4 (64 WGs x 16 cols), off = hidx&15,
// pc = off*4 + gate (lane-local gates). WxPT[n = g*64+pc][k 512]; WhP[g][kb 128][pc 64][8].
__global__ __launch_bounds__(256) void prep_w(const float* __restrict__ W,
                                              short* __restrict__ WxPT,
                                              short* __restrict__ WhP) {
  int idx = blockIdx.x * 256 + threadIdx.x;
  if (idx >= 1536 * 4096) return;
  int k = idx >> 12, col = idx & 4095;
  short b = f2bf(W[idx]);
  int gate = col >> 10, hidx = col & 1023;
  int g = hidx >> 4, off = hidx & 15;
  int pc = off * 4 + gate;
  if (k < 512) {
    WxPT[(size_t)(g * 64 + pc) * 512 + k] = b;
  } else {
    int kh = k - 512;
    WhP[(size_t)(((g * 128 + (kh >> 3)) * 64 + pc) << 3) + (kh & 7)] = b;
  }
}

// ---------------------------------------------------------------------------
// gemm_x: M=32768 (t*64+m), N=4096 (perm n = g*64+pc), K=512. BM=BN=128, BK=32.
// Output XP[t][g][m 64][pc 64] bf16.
__global__ __launch_bounds__(256) void gemm_x(const float* __restrict__ x,
                                              const short* __restrict__ WxPT,
                                              short* __restrict__ XP) {
  __shared__ short As[4096];
  __shared__ short Bs[4096];
  int tid = threadIdx.x;
  int w = tid >> 6, l = tid & 63;
  int mt = blockIdx.x >> 5, nt = blockIdx.x & 31;
  int m0 = mt * 128, n0 = nt * 128;
  f32x4 acc[4][4];
#pragma unroll
  for (int a = 0; a < 4; ++a)
#pragma unroll
    for (int b = 0; b < 4; ++b) acc[a][b] = (f32x4){0.f, 0.f, 0.f, 0.f};

  for (int ks = 0; ks < 16; ++ks) {
    int k0 = ks * 32;
#pragma unroll
    for (int it = 0; it < 2; ++it) {
      int cchunk = it * 256 + tid;  // 512 chunks of 16B
      int kb = cchunk >> 7, rc = cchunk & 127;
      const float4* ap = reinterpret_cast<const float4*>(x + (size_t)(m0 + rc) * 512 + k0 + kb * 8);
      float4 fa = ap[0], fb = ap[1];
      s16x8 av;
      av[0] = f2bf(fa.x); av[1] = f2bf(fa.y); av[2] = f2bf(fa.z); av[3] = f2bf(fa.w);
      av[4] = f2bf(fb.x); av[5] = f2bf(fb.y); av[6] = f2bf(fb.z); av[7] = f2bf(fb.w);
      s16x8 bv = *reinterpret_cast<const s16x8*>(WxPT + (size_t)(n0 + rc) * 512 + k0 + kb * 8);
      reinterpret_cast<s16x8*>(As)[cchunk] = av;
      reinterpret_cast<s16x8*>(Bs)[cchunk] = bv;
    }
    __syncthreads();
    s16x8 af[4], bfr[4];
#pragma unroll
    for (int tm = 0; tm < 4; ++tm)
      af[tm] = reinterpret_cast<s16x8*>(As)[(l >> 4) * 128 + (w >> 1) * 64 + tm * 16 + (l & 15)];
#pragma unroll
    for (int tn = 0; tn < 4; ++tn)
      bfr[tn] = reinterpret_cast<s16x8*>(Bs)[(l >> 4) * 128 + (w & 1) * 64 + tn * 16 + (l & 15)];
#pragma unroll
    for (int tm = 0; tm < 4; ++tm)
#pragma unroll
      for (int tn = 0; tn < 4; ++tn)
        acc[tm][tn] = __builtin_amdgcn_mfma_f32_16x16x32_bf16(af[tm], bfr[tn], acc[tm][tn], 0, 0, 0);
    __syncthreads();
  }
#pragma unroll
  for (int tm = 0; tm < 4; ++tm)
#pragma unroll
    for (int tn = 0; tn < 4; ++tn)
#pragma unroll
      for (int r = 0; r < 4; ++r) {
        int m = m0 + (w >> 1) * 64 + tm * 16 + (l >> 4) * 4 + r;
        int n = n0 + (w & 1) * 64 + tn * 16 + (l & 15);
        XP[(size_t)(m >> 6) * 262144 + (size_t)(n >> 6) * 4096 + (m & 63) * 64 + (n & 63)] =
            f2bf(acc[tm][tn][r]);
      }
}

// ---------------------------------------------------------------------------
// lstm_seq: 64 WGs x 256. WG g: hidden [16g,16g+16), perm-cols pc=off*4+gate (64).
// Wave w: batch rows [16w,16w+16). Lane l: m = w*16+(l&15), q4 = l>>4.
// Lane owns hidden cols g*16 + P*4 + q4 (P=0..3), all 4 gates: accP[r] = gate r.
// hqt[t&15][gblk8 0..127][m 64][j 4] u64 = tag(t)<<32 | h[8*gblk8+j+4]<<16 | h[8*gblk8+j].
__global__ __launch_bounds__(256, 1) void lstm_seq(const short* __restrict__ XP,
                                                   const short* __restrict__ WhP,
                                                   const float* __restrict__ bias,
                                                   const float* __restrict__ peep_i,
                                                   const float* __restrict__ peep_f,
                                                   const float* __restrict__ peep_o,
                                                   u64* hqt,
                                                   float* __restrict__ out) {
  __shared__ short WhS[65536];   // 128KB [kb 128][pc 64][8]
  __shared__ float outS[1024];   //   4KB [wave 4][m 16][col 16]
  int g = blockIdx.x;
  int tid = threadIdx.x, w = tid >> 6, l = tid & 63;
  {
    const s16x8* src = reinterpret_cast<const s16x8*>(WhP + (size_t)g * 65536);
    s16x8* dst = reinterpret_cast<s16x8*>(WhS);
#pragma unroll
    for (int i = 0; i < 32; ++i) dst[i * 256 + tid] = src[i * 256 + tid];
  }
  int m = w * 16 + (l & 15), q4 = l >> 4, l15 = l & 15;
  float bia[4], bja[4], bfa[4], boa[4], pia[4], pfa[4], poa[4];
#pragma unroll
  for (int P = 0; P < 4; ++P) {
    int col = g * 16 + P * 4 + q4;
    bia[P] = bias[col];
    bja[P] = bias[1024 + col];
    bfa[P] = bias[2048 + col];
    boa[P] = bias[3072 + col];
    pia[P] = peep_i[col];
    pfa[P] = peep_f[col];
    poa[P] = peep_o[col];
  }
  float cr[4] = {0.f, 0.f, 0.f, 0.f};
  s16x8* WhS16 = reinterpret_cast<s16x8*>(WhS);
  __syncthreads();

// group G: 16 dwordx4/lane (= 32 tagged u64, 8 k-chunks of 32). Load i: gblk8 index
// kb_ = (G*8+(i>>1))*4+q4; dwordx4 words: [0]=data j, [1]=tag j, [2]=data j+1, [3]=tag j+1.
#define LOADG(BANK, G)                                                                   \
  {                                                                                      \
    _Pragma("unroll") for (int i = 0; i < 16; ++i) {                                     \
      int kb_ = ((G) * 8 + (i >> 1)) * 4 + q4;                                           \
      BANK[i] = *reinterpret_cast<const i32x4*>(rdq + kb_ * 256 + m * 4 + (i & 1) * 2);  \
    }                                                                                    \
  }
// retry: bypass L1+L2 (sc0 sc1), fresh at LLC; batched issue + one drain + sched fence
#define RELOADG(BANK, G)                                                                 \
  {                                                                                      \
    _Pragma("unroll") for (int i = 0; i < 16; ++i) {                                     \
      int kb_ = ((G) * 8 + (i >> 1)) * 4 + q4;                                           \
      const u64* p_ = rdq + kb_ * 256 + m * 4 + (i & 1) * 2;                             \
      asm volatile("global_load_dwordx4 %0, %1, off sc0 sc1" : "=v"(BANK[i]) : "v"(p_)); \
    }                                                                                    \
    asm volatile("s_waitcnt vmcnt(0)" ::: "memory");                                     \
    __builtin_amdgcn_sched_barrier(0);                                                   \
  }
#define CHECKG(BANK, G)                                                                  \
  {                                                                                      \
    int guard = 0;                                                                       \
    while (true) {                                                                       \
      bool ok = true;                                                                    \
      _Pragma("unroll") for (int i = 0; i < 16; ++i) ok &=                               \
          ((unsigned)BANK[i][1] == (unsigned)t) & ((unsigned)BANK[i][3] == (unsigned)t); \
      if (__all((int)ok)) break;                                                         \
      if (++guard > (1 << 13)) break; /* fail loud, never hang */                        \
      RELOADG(BANK, G);                                                                  \
    }                                                                                    \
  }
// per chunk: reassemble B-frag (k = 8*kb_..+8) from 4 u64 payloads; 4 MFMAs (pc-blocks)
#define MFMAG(BANK, G)                                                                   \
  {                                                                                      \
    _Pragma("unroll") for (int kk2 = 0; kk2 < 8; ++kk2) {                                \
      int kb_ = ((G) * 8 + kk2) * 4 + q4;                                                \
      unsigned d0 = (unsigned)BANK[kk2 * 2][0], d1 = (unsigned)BANK[kk2 * 2][2];         \
      unsigned d2 = (unsigned)BANK[kk2 * 2 + 1][0], d3 = (unsigned)BANK[kk2 * 2 + 1][2]; \
      union { unsigned u[4]; s16x8 v; } bu;                                              \
      bu.u[0] = (d0 & 0xFFFFu) | (d1 << 16);                                             \
      bu.u[1] = (d2 & 0xFFFFu) | (d3 << 16);                                             \
      bu.u[2] = (d0 >> 16) | (d1 & 0xFFFF0000u);                                         \
      bu.u[3] = (d2 >> 16) | (d3 & 0xFFFF0000u);                                        \
      int ab = kb_ * 64 + l15;                                                           \
      s16x8 a0 = WhS16[ab];                                                              \
      s16x8 a1 = WhS16[ab + 16];                                                         \
      s16x8 a2 = WhS16[ab + 32];                                                         \
      s16x8 a3 = WhS16[ab + 48];                                                         \
      acc0 = __builtin_amdgcn_mfma_f32_16x16x32_bf16(a0, bu.v, acc0, 0, 0, 0);           \
      acc1 = __builtin_amdgcn_mfma_f32_16x16x32_bf16(a1, bu.v, acc1, 0, 0, 0);           \
      acc2 = __builtin_amdgcn_mfma_f32_16x16x32_bf16(a2, bu.v, acc2, 0, 0, 0);           \
      acc3 = __builtin_amdgcn_mfma_f32_16x16x32_bf16(a3, bu.v, acc3, 0, 0, 0);           \
    }                                                                                    \
  }
#define ELEM(ACC, P)                                                                     \
  {                                                                                      \
    float cold = cr[P];                                                                  \
    float gi = ACC[0] + bf2f(xg##P[0]) + bia[P];                                         \
    float gj = ACC[1] + bf2f(xg##P[1]) + bja[P];                                         \
    float gf = ACC[2] + bf2f(xg##P[2]) + bfa[P];                                         \
    float go = ACC[3] + bf2f(xg##P[3]) + boa[P];                                         \
    float ii = sigf(gi + cold * pia[P]);                                                 \
    float ff = sigf(gf + cold * pfa[P]);                                                 \
    float cn = ff * cold + ii * tanh_fast(gj);                                           \
    float oo = sigf(go + cn * poa[P]);                                                   \
    hv[P] = oo * tanh_fast(cn);                                                          \
    cv[P] = cn;                                                                          \
    cr[P] = cn;                                                                          \
  }

  for (int t = 0; t < SEQN; ++t) {
    // x-projection (precomputed; 4 x 8B loads; coherent via dispatch boundary)
    const short* xpb = XP + ((size_t)t * 64 + g) * 4096 + m * 64 + q4 * 4;
    s16x4 xg0 = *reinterpret_cast<const s16x4*>(xpb);
    s16x4 xg1 = *reinterpret_cast<const s16x4*>(xpb + 16);
    s16x4 xg2 = *reinterpret_cast<const s16x4*>(xpb + 32);
    s16x4 xg3 = *reinterpret_cast<const s16x4*>(xpb + 48);

    f32x4 acc0 = {0.f, 0.f, 0.f, 0.f}, acc1 = {0.f, 0.f, 0.f, 0.f};
    f32x4 acc2 = {0.f, 0.f, 0.f, 0.f}, acc3 = {0.f, 0.f, 0.f, 0.f};
    if (t > 0) {
      const u64* rdq = hqt + (size_t)(t & (DEPTH - 1)) * 32768;
      i32x4 hA[16], hB[16];
      LOADG(hA, 0);
      LOADG(hB, 1);
      CHECKG(hA, 0);
      MFMAG(hA, 0);
      LOADG(hA, 2);
      CHECKG(hB, 1);
      MFMAG(hB, 1);
      LOADG(hB, 3);
      CHECKG(hA, 2);
      MFMAG(hA, 2);
      CHECKG(hB, 3);
      MFMAG(hB, 3);
    }
    // elementwise: 4 hidden cols x 4 gates, all lane-local
    float hv[4], cv[4];
    ELEM(acc0, 0);
    ELEM(acc1, 1);
    ELEM(acc2, 2);
    ELEM(acc3, 3);
    // publish tagged h_t (tag t+1) into slot (t+1)&15: TWO exchanges/lane
    {
      u64 hi = (u64)(unsigned)(t + 1) << 32;
      u64 qa = hi | ((u64)(unsigned short)f2bf(hv[1]) << 16) | (u64)(unsigned short)f2bf(hv[0]);
      u64 qb = hi | ((u64)(unsigned short)f2bf(hv[3]) << 16) | (u64)(unsigned short)f2bf(hv[2]);
      u64* wrq = hqt + (size_t)((t + 1) & (DEPTH - 1)) * 32768;
      (void)__hip_atomic_exchange(wrq + (2 * g) * 256 + m * 4 + q4, qa, __ATOMIC_RELAXED,
                                  __HIP_MEMORY_SCOPE_AGENT);
      (void)__hip_atomic_exchange(wrq + (2 * g + 1) * 256 + m * 4 + q4, qb, __ATOMIC_RELAXED,
                                  __HIP_MEMORY_SCOPE_AGENT);
    }
    // coalesced hidden_seq store via wave-local LDS stage (16m x 16col per wave)
#pragma unroll
    for (int P = 0; P < 4; ++P) outS[w * 256 + l15 * 16 + P * 4 + q4] = hv[P];
    {
      f32x4 v = *reinterpret_cast<f32x4*>(&outS[w * 256 + (l >> 2) * 16 + (l & 3) * 4]);
      int row = w * 16 + (l >> 2), col = g * 16 + (l & 3) * 4;
      __builtin_nontemporal_store(
          v, reinterpret_cast<f32x4*>(out + (size_t)t * 65536 + (size_t)row * 1024 + col));
    }
    if (t == SEQN - 1) {
#pragma unroll
      for (int P = 0; P < 4; ++P) {
        int col = g * 16 + P * 4 + q4;
        out[33554432ull + (size_t)m * 1024 + col] = cv[P];  // c_T
        out[33619968ull + (size_t)m * 1024 + col] = hv[P];  // h_T
      }
    }
  }
#undef LOADG
#undef RELOADG
#undef CHECKG
#undef MFMAG
#undef ELEM
}

// ---------------------------------------------------------------------------
extern "C" void kernel_launch(void* const* d_in, const int* in_sizes, int n_in,
                              void* d_out, int out_size, void* d_ws, size_t ws_size,
                              hipStream_t stream) {
  const float* x      = (const float*)d_in[0];
  const float* W      = (const float*)d_in[1];
  const float* bias   = (const float*)d_in[2];
  const float* peep_i = (const float*)d_in[3];
  const float* peep_f = (const float*)d_in[4];
  const float* peep_o = (const float*)d_in[5];
  char* ws = (char*)d_ws;
  short* XP   = (short*)(ws);                  // 268435456 B  bf16 gate pre-acts
  short* WxPT = (short*)(ws + 268435456ull);   //   4194304 B  (dead after gemm_x)
  short* WhP  = (short*)(ws + 272629760ull);   //   8388608 B
  u64* hqt    = (u64*)(ws + 268435456ull);     //   4194304 B  OVERLAYS WxPT (16 x 256KB)
  prep_w<<<24576, 256, 0, stream>>>(W, WxPT, WhP);
  gemm_x<<<8192, 256, 0, stream>>>(x, WxPT, XP);
  // memset AFTER gemm_x (stream-ordered): WxPT is dead, hqt takes its space.
  // zero tags every launch: stale tags from a prior replay must never alias this run.
  (void)hipMemsetAsync(hqt, 0, 4194304ull, stream);
  lstm_seq<<<NWG, 256, 0, stream>>>(XP, WhP, bias, peep_i, peep_f, peep_o, hqt,
                                    (float*)d_out);
}

// Round 12
// 3031.188 us; speedup vs baseline: 1.2173x; 1.1807x over previous
//
#include <hip/hip_runtime.h>
#include <hip/hip_bf16.h>

// PeepholeLSTM: SEQ=512, BATCH=64, IN=512, HS=1024, FORGET_BIAS=0
// out = [hidden_seq (512*64*1024) | c_T (64*1024) | h_T (64*1024)] f32
//
// Round-12: round-9 fused config (pc=32, NWG=128) + readiness GATE before consume.
//   r11 refuted aggregate-BW model (half volume -> slower): regime is per-WG latency
//   + retry rounds. Retries exist because consumers load before producers publish,
//   poisoning L2 with stale-tag lines (then everything rides the sc0sc1 bypass).
//   Gate protocol (seqlock ordering):
//     producer wave: data exchanges -> s_waitcnt vmcnt(0) (acked at LLC) -> LDS
//     monotonic counter; 4th wave writes gate[slot][g] (u64, own 64B line, 8KB/slot).
//     consumer wave: poll 2 gate u64/lane (all 128 producers) sc0sc1 + s_sleep backoff,
//     THEN bulk plain loads: guaranteed fresh at LLC -> no poisoning -> 16 WGs/XCD
//     share each L2 fill; embedded tags remain as correctness net (rare stale-L2
//     survivor -> sc0sc1 retry). No syncthreads in loop; waves stay independent.

#define SEQN 512
#define BATCH 64
#define INDIM 512
#define HSZ 1024
#define NWG 128
#define DEPTH 16

typedef __attribute__((ext_vector_type(8))) short s16x8;
typedef __attribute__((ext_vector_type(4))) float f32x4;
typedef __attribute__((ext_vector_type(2))) float f32x2;
typedef __attribute__((ext_vector_type(4))) int i32x4;
typedef unsigned long long u64;

__device__ __forceinline__ short f2bf(float f) {
  __hip_bfloat16 b = __float2bfloat16(f);
  short s;
  __builtin_memcpy(&s, &b, 2);
  return s;
}
__device__ __forceinline__ float sigf(float x) { return 1.f / (1.f + __expf(-x)); }
__device__ __forceinline__ float tanh_fast(float x) { return 2.f / (1.f + __expf(-2.f * x)) - 1.f; }

// ---------------------------------------------------------------------------
// prep_w: col = gate*1024 + hidx; hidx = g*8+off; pc = off*4+gate.
__global__ __launch_bounds__(256) void prep_w(const float* __restrict__ W,
                                              short* __restrict__ WxP,
                                              short* __restrict__ WhP) {
  int idx = blockIdx.x * 256 + threadIdx.x;
  if (idx >= 1536 * 4096) return;
  int k = idx >> 12, col = idx & 4095;
  short b = f2bf(W[idx]);
  int gate = col >> 10, hidx = col & 1023;
  int g = hidx >> 3, off = hidx & 7;
  int pc = off * 4 + gate;
  if (k < 512) {
    WxP[(size_t)(((g * 64 + (k >> 3)) * 32 + pc) << 3) + (k & 7)] = b;
  } else {
    int kh = k - 512;
    WhP[(size_t)(((g * 128 + (kh >> 3)) * 32 + pc) << 3) + (kh & 7)] = b;
  }
}

// ---------------------------------------------------------------------------
// prep_x: x[t][m][k] f32 -> xbp[t][kb][m][8] bf16.
__global__ __launch_bounds__(256) void prep_x(const float* __restrict__ x,
                                              short* __restrict__ xbp) {
  int idx = blockIdx.x * 256 + threadIdx.x;
  if (idx >= SEQN * 64 * 64) return;
  int kb = idx & 63, m = (idx >> 6) & 63, t = idx >> 12;
  const float4* xp = reinterpret_cast<const float4*>(x + ((size_t)t * 64 + m) * 512 + kb * 8);
  float4 a = xp[0], c = xp[1];
  s16x8 v;
  v[0] = f2bf(a.x); v[1] = f2bf(a.y); v[2] = f2bf(a.z); v[3] = f2bf(a.w);
  v[4] = f2bf(c.x); v[5] = f2bf(c.y); v[6] = f2bf(c.z); v[7] = f2bf(c.w);
  reinterpret_cast<s16x8*>(xbp)[((size_t)t * 64 + kb) * 64 + m] = v;
}

// ---------------------------------------------------------------------------
// lstm_seq: 128 WGs x 256. WG g: hidden [8g,8g+8). Wave w: batch rows [16w,16w+16).
// Lane l: m = w*16+(l&15), q4 = l>>4, hidden cols c0 = 8g+q4, c1 = c0+4, all 4 gates.
// hqt[t&15][gsrc 128][m 64][j 4] u64 = tag(t)<<32 | h[8gsrc+j+4]<<16 | h[8gsrc+j].
// gates[t&15][g 128] u64 (stride 8 u64 = 64B/line): == t when producer g's step-t-1
// data is acked at the LLC (written by the 4th wave after its vmcnt(0)).
__global__ __launch_bounds__(256, 1) void lstm_seq(const short* __restrict__ xbp,
                                                   const short* __restrict__ WhP,
                                                   const short* __restrict__ WxP,
                                                   const float* __restrict__ bias,
                                                   const float* __restrict__ peep_i,
                                                   const float* __restrict__ peep_f,
                                                   const float* __restrict__ peep_o,
                                                   u64* hqt,
                                                   u64* gates,
                                                   float* __restrict__ out) {
  __shared__ short WhS[32768];   // 64KB [kb 128][pc 32][8]
  __shared__ short WxS[16384];   // 32KB [kb  64][pc 32][8]
  __shared__ float outS[512];    //  2KB
  __shared__ unsigned ctrS;      // monotonic wave-completion counter
  int g = blockIdx.x;
  int tid = threadIdx.x, w = tid >> 6, l = tid & 63;
  {
    const s16x8* src = reinterpret_cast<const s16x8*>(WhP + (size_t)g * 32768);
    s16x8* dst = reinterpret_cast<s16x8*>(WhS);
#pragma unroll
    for (int i = 0; i < 16; ++i) dst[i * 256 + tid] = src[i * 256 + tid];
    const s16x8* src2 = reinterpret_cast<const s16x8*>(WxP + (size_t)g * 16384);
    s16x8* dst2 = reinterpret_cast<s16x8*>(WxS);
#pragma unroll
    for (int i = 0; i < 8; ++i) dst2[i * 256 + tid] = src2[i * 256 + tid];
  }
  if (tid == 0) ctrS = 0;
  int m = w * 16 + (l & 15), q4 = l >> 4, l15 = l & 15;
  int c0 = g * 8 + q4, c1 = c0 + 4;
  float bi0 = bias[c0], bj0 = bias[1024 + c0], bf0 = bias[2048 + c0], bo0 = bias[3072 + c0];
  float bi1 = bias[c1], bj1 = bias[1024 + c1], bf1 = bias[2048 + c1], bo1 = bias[3072 + c1];
  float pi0 = peep_i[c0], pf0 = peep_f[c0], po0 = peep_o[c0];
  float pi1 = peep_i[c1], pf1 = peep_f[c1], po1 = peep_o[c1];
  float cr0 = 0.f, cr1 = 0.f;
  s16x8* WhS16 = reinterpret_cast<s16x8*>(WhS);
  s16x8* WxS16 = reinterpret_cast<s16x8*>(WxS);
  __syncthreads();

// group G: 16 dwordx4/lane (= 32 tagged u64, 8 kb-blocks). PLAIN loads: gate guarantees
// freshness at LLC; L2 fill shared by the XCD's 16 WGs. Tags = correctness net only.
#define LOADG(BANK, G)                                                                   \
  {                                                                                      \
    _Pragma("unroll") for (int i = 0; i < 16; ++i) {                                     \
      int kb_ = ((G) * 8 + (i >> 1)) * 4 + q4;                                           \
      BANK[i] = *reinterpret_cast<const i32x4*>(rdq + kb_ * 256 + m * 4 + (i & 1) * 2);  \
    }                                                                                    \
  }
// rare retry (stale L2 survivor): bypass L1+L2, fresh at LLC
#define RELOADG(BANK, G)                                                                 \
  {                                                                                      \
    _Pragma("unroll") for (int i = 0; i < 16; ++i) {                                     \
      int kb_ = ((G) * 8 + (i >> 1)) * 4 + q4;                                           \
      const u64* p_ = rdq + kb_ * 256 + m * 4 + (i & 1) * 2;                             \
      asm volatile("global_load_dwordx4 %0, %1, off sc0 sc1" : "=v"(BANK[i]) : "v"(p_)); \
    }                                                                                    \
    asm volatile("s_waitcnt vmcnt(0)" ::: "memory");                                     \
    __builtin_amdgcn_sched_barrier(0);                                                   \
  }
#define CHECKG(BANK, G)                                                                  \
  {                                                                                      \
    int guard = 0;                                                                       \
    while (true) {                                                                       \
      bool ok = true;                                                                    \
      _Pragma("unroll") for (int i = 0; i < 16; ++i) ok &=                               \
          ((unsigned)BANK[i][1] == (unsigned)t) & ((unsigned)BANK[i][3] == (unsigned)t); \
      if (__all((int)ok)) break;                                                         \
      if (++guard > (1 << 13)) break; /* fail loud, never hang */                        \
      RELOADG(BANK, G);                                                                  \
    }                                                                                    \
  }
#define MFMAG(BANK, G)                                                                   \
  {                                                                                      \
    _Pragma("unroll") for (int kk2 = 0; kk2 < 8; ++kk2) {                                \
      int kb_ = ((G) * 8 + kk2) * 4 + q4;                                                \
      unsigned d0 = (unsigned)BANK[kk2 * 2][0], d1 = (unsigned)BANK[kk2 * 2][2];         \
      unsigned d2 = (unsigned)BANK[kk2 * 2 + 1][0], d3 = (unsigned)BANK[kk2 * 2 + 1][2]; \
      union { unsigned u[4]; s16x8 v; } bu;                                              \
      bu.u[0] = (d0 & 0xFFFFu) | (d1 << 16);                                             \
      bu.u[1] = (d2 & 0xFFFFu) | (d3 << 16);                                             \
      bu.u[2] = (d0 >> 16) | (d1 & 0xFFFF0000u);                                         \
      bu.u[3] = (d2 >> 16) | (d3 & 0xFFFF0000u);                                        \
      s16x8 a0 = WhS16[kb_ * 32 + l15];                                                  \
      s16x8 a1 = WhS16[kb_ * 32 + 16 + l15];                                             \
      acc0 = __builtin_amdgcn_mfma_f32_16x16x32_bf16(a0, bu.v, acc0, 0, 0, 0);           \
      acc1 = __builtin_amdgcn_mfma_f32_16x16x32_bf16(a1, bu.v, acc1, 0, 0, 0);           \
    }                                                                                    \
  }

  for (int t = 0; t < SEQN; ++t) {
    f32x4 acc0 = {0.f, 0.f, 0.f, 0.f}, acc1 = {0.f, 0.f, 0.f, 0.f};
    // ---- x-projection (h-independent; fills producer-publish window) ----
    {
      const s16x8* xt = reinterpret_cast<const s16x8*>(xbp) + (size_t)t * 4096;
#pragma unroll 4
      for (int kk = 0; kk < 16; ++kk) {
        int kb = kk * 4 + q4;
        s16x8 bx = xt[kb * 64 + m];
        s16x8 a0 = WxS16[kb * 32 + l15];
        s16x8 a1 = WxS16[kb * 32 + 16 + l15];
        acc0 = __builtin_amdgcn_mfma_f32_16x16x32_bf16(a0, bx, acc0, 0, 0, 0);
        acc1 = __builtin_amdgcn_mfma_f32_16x16x32_bf16(a1, bx, acc1, 0, 0, 0);
      }
    }
    if (t > 0) {
      const u64* rdq = hqt + (size_t)(t & (DEPTH - 1)) * 32768;
      // ---- GATE: wait until every producer's step-(t-1) data is acked at the LLC ----
      {
        const u64* gq = gates + (size_t)(t & (DEPTH - 1)) * 1024;
        const u64* p0 = gq + (size_t)(2 * l) * 8;
        const u64* p1 = gq + (size_t)(2 * l + 1) * 8;
        int guard = 0;
        while (true) {
          u64 v0, v1;
          asm volatile("global_load_dwordx2 %0, %1, off sc0 sc1" : "=v"(v0) : "v"(p0));
          asm volatile("global_load_dwordx2 %0, %1, off sc0 sc1" : "=v"(v1) : "v"(p1));
          asm volatile("s_waitcnt vmcnt(0)" ::: "memory");
          __builtin_amdgcn_sched_barrier(0);
          if (__all((int)((v0 == (u64)(unsigned)t) & (v1 == (u64)(unsigned)t)))) break;
          if (++guard > (1 << 15)) break;  // fail loud (tags still verify), never hang
          __builtin_amdgcn_s_sleep(2);
        }
      }
      // ---- consume: 4 pipelined groups, 2 reg banks (plain loads, L2-shared) ----
      i32x4 hA[16], hB[16];
      LOADG(hA, 0);
      LOADG(hB, 1);
      CHECKG(hA, 0);
      MFMAG(hA, 0);
      LOADG(hA, 2);
      CHECKG(hB, 1);
      MFMAG(hB, 1);
      LOADG(hB, 3);
      CHECKG(hA, 2);
      MFMAG(hA, 2);
      CHECKG(hB, 3);
      MFMAG(hB, 3);
    }
    // ---- elementwise (lane-local: all 4 gates of c0 and c1) ----
    float i0 = sigf(acc0[0] + bi0 + cr0 * pi0);
    float f0 = sigf(acc0[2] + bf0 + cr0 * pf0);
    float cn0 = f0 * cr0 + i0 * tanh_fast(acc0[1] + bj0);
    float o0 = sigf(acc0[3] + bo0 + cn0 * po0);
    float h0 = o0 * tanh_fast(cn0);
    cr0 = cn0;
    float i1 = sigf(acc1[0] + bi1 + cr1 * pi1);
    float f1 = sigf(acc1[2] + bf1 + cr1 * pf1);
    float cn1 = f1 * cr1 + i1 * tanh_fast(acc1[1] + bj1);
    float o1 = sigf(acc1[3] + bo1 + cn1 * po1);
    float h1 = o1 * tanh_fast(cn1);
    cr1 = cn1;
    // ---- publish tagged h_t (tag t+1) -> drain -> gate fan-in ----
    {
      u64 q = ((u64)(unsigned)(t + 1) << 32) |
              ((u64)(unsigned short)f2bf(h1) << 16) | (u64)(unsigned short)f2bf(h0);
      (void)__hip_atomic_exchange(
          hqt + (size_t)((t + 1) & (DEPTH - 1)) * 32768 + g * 256 + m * 4 + q4, q,
          __ATOMIC_RELAXED, __HIP_MEMORY_SCOPE_AGENT);
    }
    asm volatile("s_waitcnt vmcnt(0)" ::: "memory");  // data acked at LLC
    if (l == 0) {
      unsigned old = atomicAdd(&ctrS, 1u);  // LDS, monotonic (4 waves per step)
      if (old == 4u * (unsigned)t + 3u) {   // last wave of this WG this step
        (void)__hip_atomic_exchange(
            gates + (size_t)((t + 1) & (DEPTH - 1)) * 1024 + (size_t)g * 8,
            (u64)(unsigned)(t + 1), __ATOMIC_RELAXED, __HIP_MEMORY_SCOPE_AGENT);
      }
    }
    // ---- coalesced hidden_seq store via wave-local LDS stage ----
    outS[w * 128 + l15 * 8 + q4] = h0;
    outS[w * 128 + l15 * 8 + q4 + 4] = h1;
    {
      f32x2 v = *reinterpret_cast<f32x2*>(&outS[w * 128 + (l >> 2) * 8 + (l & 3) * 2]);
      int row = w * 16 + (l >> 2), col = g * 8 + (l & 3) * 2;
      __builtin_nontemporal_store(
          v, reinterpret_cast<f32x2*>(out + (size_t)t * 65536 + (size_t)row * 1024 + col));
    }
    if (t == SEQN - 1) {
      out[33554432ull + (size_t)m * 1024 + c0] = cn0;  // c_T
      out[33554432ull + (size_t)m * 1024 + c1] = cn1;
      out[33619968ull + (size_t)m * 1024 + c0] = h0;   // h_T
      out[33619968ull + (size_t)m * 1024 + c1] = h1;
    }
  }
#undef LOADG
#undef RELOADG
#undef CHECKG
#undef MFMAG
}

// ---------------------------------------------------------------------------
extern "C" void kernel_launch(void* const* d_in, const int* in_sizes, int n_in,
                              void* d_out, int out_size, void* d_ws, size_t ws_size,
                              hipStream_t stream) {
  const float* x      = (const float*)d_in[0];
  const float* W      = (const float*)d_in[1];
  const float* bias   = (const float*)d_in[2];
  const float* peep_i = (const float*)d_in[3];
  const float* peep_f = (const float*)d_in[4];
  const float* peep_o = (const float*)d_in[5];
  char* ws = (char*)d_ws;
  short* WxP = (short*)(ws);                   //  4194304 B
  short* WhP = (short*)(ws + 4194304ull);      //  8388608 B
  short* xbp = (short*)(ws + 12582912ull);     // 33554432 B
  u64* hqt   = (u64*)(ws + 46137344ull);       //  4194304 B (16 x 256KB tagged h slots)
  u64* gates = (u64*)(ws + 50331648ull);       //   131072 B (16 x 8KB gate slots)
  // zero tags+gates every launch: stale values from a prior replay must never alias
  // this run's expected tag sequence (hqt and gates are contiguous: one memset)
  (void)hipMemsetAsync(hqt, 0, 4325376ull, stream);
  prep_w<<<24576, 256, 0, stream>>>(W, WxP, WhP);
  prep_x<<<8192, 256, 0, stream>>>(x, xbp);
  lstm_seq<<<NWG, 256, 0, stream>>>(xbp, WhP, WxP, bias, peep_i, peep_f, peep_o, hqt,
                                    gates, (float*)d_out);
}